// Round 19
// baseline (97.714 us; speedup 1.0000x reference)
//
#include <hip/hip_runtime.h>
#include <hip/hip_bf16.h>

// Round 19: occupancy doublings on the serial chain.
//  - k_env: 1024 blocks x 4 atoms, er 4 rows (LDS 23.8KB -> 4 blocks/CU).
//    GEMM A-row read (l&15)&3; D rows 4-15 garbage (unused). env-MFMA on
//    waves 0-3 (1 atom each).
//  - k_xt: 512 blocks x 256 thr x 8 atoms (9.5KB LDS, 2 blocks/CU).
//  - k_init unchanged (r18-verified).

#define DEG 32
#define NA 4096
#define NP 131072

typedef __hip_bfloat16 bf16;
typedef __attribute__((ext_vector_type(8))) short short8v;
typedef __attribute__((ext_vector_type(4))) float f32x4;

#define Z0F 16.27906976744186f
#define DZ  1.0526315789473684f

__device__ __forceinline__ float frcp(float x){ return __builtin_amdgcn_rcpf(x); }
__device__ __forceinline__ float sigmoid_f(float x){ return frcp(1.f + __expf(-x)); }
__device__ __forceinline__ float tanh_f(float x){ return 1.f - 2.f*frcp(__expf(2.f*x)+1.f); }
__device__ __forceinline__ float softplus_f(float x){ return fmaxf(x,0.f) + __logf(1.f + __expf(-fabsf(x))); }
__device__ __forceinline__ unsigned bf16pack(float lo, float hi){
  unsigned ul = __float_as_uint(lo), uh = __float_as_uint(hi);
  unsigned rl = (ul + 0x7fffu + ((ul>>16)&1u)) >> 16;
  unsigned rh = (uh + 0x7fffu + ((uh>>16)&1u)) & 0xffff0000u;
  return rl | rh;
}
__device__ __forceinline__ unsigned short b16u(float v){
  unsigned u = __float_as_uint(v);
  return (unsigned short)((u + 0x7fffu + ((u>>16)&1u)) >> 16);
}
union UU { unsigned u[4]; short8v v; };
union U4 { uint4 q; short8v v; unsigned u[4]; };

// write one 16x16 D-tile (rows s<20, cols f<40) into er bf16-pair buffer (r6)
__device__ __forceinline__ void wr_tile(unsigned* er, f32x4 D, int M, int N,
                                        int lg, int lr, int l){
  #pragma unroll
  for(int r=0;r<4;r++){
    float vd = D[r];
    float pr = __shfl_xor(vd, 1);
    int s = M*16 + lg*4 + r, f = N*16 + lr;
    if(!(l&1) && s<20 && f<40) er[s*20 + (f>>1)] = bf16pack(vd, pr);
  }
}

// ---- ivcu staging helper: own 16 atoms' 512 pairs from coords ----------------
__device__ __forceinline__ void stage_ivcu(float2* ivcu, unsigned char* nb8,
    int t, int abase, int nbase,
    const int* __restrict__ ps, const float* __restrict__ coord){
  int pg = abase*DEG + t;
  int i = abase + (t>>5);
  int j = ps[pg];
  float dx = coord[i*3+0]-coord[j*3+0];
  float dy = coord[i*3+1]-coord[j*3+1];
  float dz = coord[i*3+2]-coord[j*3+2];
  float d = sqrtf(dx*dx+dy*dy+dz*dz + 1e-12f);
  float cu = 0.f;
  if (d < 7.5f){ float c = __cosf(d * 0.20943951023931953f); cu = c*c; } // pi/15
  ivcu[t] = make_float2(1.f/d, cu);
  nb8[t] = (unsigned char)(j - nbase);
}

// ---- merged init kernel LDS (4672 words = 18.7 KB) ---------------------------
#define I_IVCU 0
#define I_NB   1024
#define I_INDF 1152
#define I_ENV0 1792
#define I_Y0A  3392
#define I_Y0B  4032
#define I_XIN  1152
#define I_WTS  1280
#define I_EV1  2980
#define I_YA   3300
#define I_YB   3620
#define I_SMEM 4672

// ---------------- k_init: prep | f0 | xt0 | xt1 (r18-verified) ---------------
__global__ __launch_bounds__(512) void k_init(
    const int* __restrict__ ps, const int* __restrict__ species,
    const float* __restrict__ coord, const float* __restrict__ xh,
    const float* __restrict__ xraw,
    const float* __restrict__ pw0, const float* __restrict__ pb1,
    const float* __restrict__ Wint, const float* __restrict__ Wself,
    const float* __restrict__ h0_iw, const float* __restrict__ h0_sw,
    const float* __restrict__ h0_sb, const float* __restrict__ h0_aw,
    const float* __restrict__ h0_ab,
    const float* __restrict__ h1_iw, const float* __restrict__ h1_sw,
    const float* __restrict__ h1_sb, const float* __restrict__ h1_aw,
    const float* __restrict__ h1_ab,
    unsigned short* __restrict__ svA, unsigned* __restrict__ Amf,
    bf16* __restrict__ Wmf, float* __restrict__ proj0,
    float* __restrict__ c_g, unsigned* __restrict__ h_p,
    unsigned* __restrict__ xt_p0, unsigned* __restrict__ xt_p1)
{
  __shared__ float smem[I_SMEM];
  const int b = blockIdx.x, t = threadIdx.x;

  if (b < 256){
    int p = b*512 + t;
    int i = p>>5, j = ps[p];
    float dx = coord[i*3+0]-coord[j*3+0];
    float dy = coord[i*3+1]-coord[j*3+1];
    float dz = coord[i*3+2]-coord[j*3+2];
    float d = sqrtf(dx*dx+dy*dy+dz*dz + 1e-12f);
    float cu = 0.f;
    if (d < 7.5f){ float c = __cosf(d * 0.20943951023931953f); cu = c*c; }
    float z0 = (1.f/d - 0.2f)*Z0F;
    int atom = p>>5, k = p&31;
    float sv[20], svn[20];
    #pragma unroll
    for(int s=0;s<20;s++){
      float z = z0 - (float)s*DZ;
      sv[s] = cu*__expf(-0.5f*z*z);
    }
    #pragma unroll
    for(int s=0;s<20;s++) svn[s] = __shfl_down(sv[s], 1);
    #pragma unroll
    for(int s=0;s<20;s++) svA[atom*640 + s*32 + k] = b16u(sv[s]);
    if (!(k&1)){
      int lg = k>>3, q = (k>>1)&3;
      #pragma unroll
      for(int s=0;s<20;s++){
        int lr = s&15, fr = s>>4;
        Amf[atom*512 + (lg*16+lr)*8 + fr*4 + q] = bf16pack(sv[s], svn[s]);
      }
    } else {
      int idx = k>>1;
      int lg2 = idx>>2, q2 = idx&3;
      #pragma unroll
      for(int j2=0;j2<12;j2++){
        int lr = 4+j2;
        Amf[atom*512 + (lg2*16+lr)*8 + 4 + q2] = 0u;
      }
    }
    return;
  }
  if (b < 391){
    int tid = (b-256)*512 + t;    // < 69120 exactly
    int j = tid & 7, l = (tid>>3) & 63, gt = (tid>>9)%5, slab = tid/2560;
    int k = slab*32 + ((l>>4)<<3) + j;
    int g = gt*16 + (l&15);
    float v = 0.f;
    if (k < 800)      v = Wint[k*80+g];
    else if (k < 840) v = Wself[(k-800)*80+g];
    Wmf[tid] = __float2bfloat16(v);
    return;
  }
  if (b < 399){
    int tid = (b-391)*512 + t;
    if (tid < NA){
      int sp = species[tid];
      float f0 = (sp==1)?1.f:0.f, f1 = (sp==8)?1.f:0.f;
      proj0[tid] = pb1[0] + f0*pw0[0] + f1*pw0[1] + xh[tid*3+0]*pw0[2]
                 + xh[tid*3+1]*pw0[3] + xh[tid*3+2]*pw0[4];
    }
    return;
  }

  float2* ivcu = (float2*)(smem + I_IVCU);
  unsigned char* nb8 = (unsigned char*)(smem + I_NB);

  if (b < 655){
    int blk = b - 399;
    int mol = blk & 31, sib = blk >> 5;
    int nbase = mol*128, abase = nbase + sib*16;
    float* indf = smem + I_INDF;
    float* env0 = smem + I_ENV0;
    float* y0a  = smem + I_Y0A;
    float* y0b  = smem + I_Y0B;
    stage_ivcu(ivcu, nb8, t, abase, nbase, ps, coord);
    if (t < 128){
      int sp = species[nbase+t];
      indf[t*5+0] = (sp==1)?1.f:0.f;
      indf[t*5+1] = (sp==8)?1.f:0.f;
      indf[t*5+2] = xh[(nbase+t)*3+0];
      indf[t*5+3] = xh[(nbase+t)*3+1];
      indf[t*5+4] = xh[(nbase+t)*3+2];
    }
    __syncthreads();
    for(int task=t; task<1600; task+=512){
      int a = task/100, e = task%100, s = e/5, f = e%5;
      const float2* ivr = ivcu + a*32;
      const unsigned char* nbr = nb8 + a*32;
      float sz = (float)s*DZ, acc = 0.f;
      for(int k=0;k<32;k++){
        float2 vc = ivr[k];
        float z = (vc.x-0.2f)*Z0F - sz;
        acc += vc.y*__expf(-0.5f*z*z)*indf[nbr[k]*5+f];
      }
      env0[a*100+e] = acc;
    }
    __syncthreads();
    for(int task=t; task<640; task+=512){
      int a=task/40, o=task%40, row=(sib*16)+a;
      float acc = h0_sb[o];
      #pragma unroll
      for(int f=0;f<5;f++) acc += indf[row*5+f]*h0_sw[f*40+o];
      for(int e=0;e<100;e++) acc += env0[a*100+e]*h0_iw[e*40+o];
      y0a[a*40+o] = softplus_f(acc);
    }
    __syncthreads();
    float* cur = y0a; float* nxt = y0b;
    for(int l=0;l<3;l++){
      for(int task=t; task<640; task+=512){
        int a=task/40, o=task%40;
        float acc = h0_ab[l*40+o];
        for(int f=0;f<40;f++) acc += cur[a*40+f]*h0_aw[l*1600+f*40+o];
        nxt[a*40+o] = softplus_f(acc);
      }
      __syncthreads();
      float* tswap=cur; cur=nxt; nxt=tswap;
    }
    if (t < 320){ int a=t/20,u=t%20; c_g[(abase+a)*20+u] = cur[a*40+u]; }
    if (t < 160){ int a=t/10,p=t%10;
      h_p[NA*10 + (abase+a)*10+p] = bf16pack(cur[a*40+20+2*p], cur[a*40+21+2*p]); }
    return;
  }

  {
    int sel = (b < 911) ? 0 : 1;
    int blk = b - (sel ? 911 : 655);
    int mol = blk & 31, sib = blk >> 5;
    int nbase = mol*128, abase = nbase + sib*16;
    float* xin = smem + I_XIN;
    float* wts = smem + I_WTS;
    float* ev1 = smem + I_EV1;
    float* yA  = smem + I_YA;
    float* yB  = smem + I_YB;
    unsigned* xt_p = sel ? xt_p1 : xt_p0;

    stage_ivcu(ivcu, nb8, t, abase, nbase, ps, coord);
    if (t < 128) xin[t] = xraw[(nbase+t)*2+sel];
    for(int i=t;i<1700;i+=512){
      float v;
      if(i<400){ int o=i/20,s=i%20; v=h1_iw[s*20+o]; }
      else if(i<420) v=h1_sw[i-400];
      else if(i<440) v=h1_sb[i-420];
      else if(i<1640){ int q=i-440,L=q/400,rem=q%400,o=rem/20,f=rem%20; v=h1_aw[L*400+f*20+o]; }
      else v=h1_ab[i-1640];
      wts[i]=v;
    }
    __syncthreads();
    if (t < 320){
      int a=t/20, s=t%20;
      const float2* ivr = ivcu + a*32;
      const unsigned char* nbr = nb8 + a*32;
      float sz=(float)s*DZ, acc=0.f;
      for(int k=0;k<32;k++){
        float2 vc = ivr[k];
        float z = (vc.x-0.2f)*Z0F - sz;
        acc += vc.y*__expf(-0.5f*z*z)*xin[nbr[k]];
      }
      ev1[t] = acc;
    }
    __syncthreads();
    if (t < 320){
      int a=t/20, o=t%20;
      float acc = wts[420+o] + xin[sib*16+a]*wts[400+o];
      const float* e = ev1 + a*20; const float* w = wts + o*20;
      #pragma unroll
      for(int s=0;s<20;s++) acc += e[s]*w[s];
      yA[t] = softplus_f(acc);
    }
    __syncthreads();
    #pragma unroll
    for(int L=0;L<2;L++){
      const float* src = (L==0)? yA : yB;
      float* dst       = (L==0)? yB : yA;
      if (t < 320){
        int a=t/20, o=t%20;
        float acc = wts[1640+L*20+o];
        const float* sr = src + a*20; const float* w = wts + 440 + L*400 + o*20;
        #pragma unroll
        for(int f=0;f<20;f++) acc += sr[f]*w[f];
        dst[t] = softplus_f(acc);
      }
      __syncthreads();
    }
    if (t < 160){
      int a=t/10, p=t%10, o0=2*p, o1=o0+1;
      const float* e = yA + a*20;
      float a0 = wts[1680+o0], a1 = wts[1680+o1];
      const float* wA = wts + 1240 + o0*20;
      const float* wB = wA + 20;
      #pragma unroll
      for(int f=0;f<20;f++){ a0 += e[f]*wA[f]; a1 += e[f]*wB[f]; }
      xt_p[(abase+a)*10+p] = bf16pack(softplus_f(a0), softplus_f(a1));
    }
  }
}

// ---------------- k_xt: 512 blocks x 256 thr x 8 atoms -----------------------
#define X_XIN 0
#define X_NB  128     // u8[256] = 64 w
#define X_WTS 192
#define X_EV1 1892
#define X_YA  2052
#define X_YB  2212
#define X_SMEM 2372
__global__ __launch_bounds__(256) void k_xt(
    const int* __restrict__ ps, const unsigned short* __restrict__ svA,
    const float* __restrict__ x0g,
    const float* __restrict__ h1_iw, const float* __restrict__ h1_sw,
    const float* __restrict__ h1_sb, const float* __restrict__ h1_aw,
    const float* __restrict__ h1_ab,
    unsigned* __restrict__ xt_p)
{
  __shared__ float smem[X_SMEM];
  const int t = threadIdx.x;
  const int mol = blockIdx.x & 31, sib = blockIdx.x >> 5;  // sib in [0,16)
  const int nbase = mol*128;
  const int abase = nbase + sib*8;                          // own 8 atoms
  float* xin = smem + X_XIN;
  unsigned char* nb8 = (unsigned char*)(smem + X_NB);
  float* wts = smem + X_WTS;
  float* ev1 = smem + X_EV1;
  float* yA  = smem + X_YA;
  float* yB  = smem + X_YB;

  if (t < 128) xin[t] = x0g[nbase+t];
  nb8[t] = (unsigned char)(ps[abase*DEG+t] - nbase);       // 256 pairs
  for(int i=t;i<1700;i+=256){
    float v;
    if(i<400){ int o=i/20,s=i%20; v=h1_iw[s*20+o]; }
    else if(i<420) v=h1_sw[i-400];
    else if(i<440) v=h1_sb[i-420];
    else if(i<1640){ int q=i-440,L=q/400,rem=q%400,o=rem/20,f=rem%20; v=h1_aw[L*400+f*20+o]; }
    else v=h1_ab[i-1640];
    wts[i]=v;
  }
  __syncthreads();

  if (t < 160){
    int a=t/20, s=t%20;
    const uint4* sp4 = (const uint4*)(svA + (abase+a)*640 + s*32);
    const unsigned char* nbr = nb8 + a*32;
    float acc = 0.f;
    #pragma unroll
    for(int c4=0;c4<4;c4++){
      uint4 w = sp4[c4];
      unsigned wu[4] = {w.x,w.y,w.z,w.w};
      #pragma unroll
      for(int j=0;j<4;j++){
        float flo = __uint_as_float(wu[j]<<16);
        float fhi = __uint_as_float(wu[j] & 0xffff0000u);
        int k = c4*8 + 2*j;
        acc += flo*xin[nbr[k]] + fhi*xin[nbr[k+1]];
      }
    }
    ev1[t] = acc;
  }
  __syncthreads();
  if (t < 160){
    int a=t/20, o=t%20;
    float acc = wts[420+o] + xin[sib*8+a]*wts[400+o];
    const float* e = ev1 + a*20; const float* w = wts + o*20;
    #pragma unroll
    for(int s=0;s<20;s++) acc += e[s]*w[s];
    yA[t] = softplus_f(acc);
  }
  __syncthreads();
  #pragma unroll
  for(int L=0;L<2;L++){
    const float* src = (L==0)? yA : yB;
    float* dst       = (L==0)? yB : yA;
    if (t < 160){
      int a=t/20, o=t%20;
      float acc = wts[1640+L*20+o];
      const float* sr = src + a*20; const float* w = wts + 440 + L*400 + o*20;
      #pragma unroll
      for(int f=0;f<20;f++) acc += sr[f]*w[f];
      dst[t] = softplus_f(acc);
    }
    __syncthreads();
  }
  if (t < 80){
    int a=t/10, p=t%10, o0=2*p, o1=o0+1;
    const float* e = yA + a*20;
    float a0 = wts[1680+o0], a1 = wts[1680+o1];
    const float* wA = wts + 1240 + o0*20;
    const float* wB = wA + 20;
    #pragma unroll
    for(int f=0;f<20;f++){ a0 += e[f]*wA[f]; a1 += e[f]*wB[f]; }
    xt_p[(abase+a)*10+p] = bf16pack(softplus_f(a0), softplus_f(a1));
  }
}

// ---------------- k_env: 1024 blocks x 4 atoms; MFMA env + GEMM + LSTM -------
// er 4 rows; GEMM A-row read (l&15)&3; D rows 4-15 garbage (unused).
#define E_XHP 0          // 128x21 = 2688
#define E_NB  2688       // u8[128] = 32 w
#define E_PRJ 2720       // 16
#define E_PW1 2736       // 24
#define E_ER  2760       // 4*436 = 1744
#define E_TMP (E_ER+1744)    // 1280 (16 rows; only 0-3 read)
#define E_RED (E_TMP+1280)   // 80
#define E_HT  (E_RED+80)     // 80
#define E_SMEM (E_HT+80)     // 5944 w = 23.8 KB
__global__ __launch_bounds__(512) void k_env(
    const int* __restrict__ ps, const unsigned* __restrict__ Amf,
    const unsigned* __restrict__ xt_p, const unsigned* __restrict__ h_p,
    int rpar, int wpar,
    const bf16* __restrict__ Wmf, const float* __restrict__ Wb,
    const float* __restrict__ pw1, const float* __restrict__ proj0,
    float* __restrict__ c_g, unsigned* __restrict__ h_po,
    float* __restrict__ x0g, float* __restrict__ outp, int out_col)
{
  __shared__ float smem[E_SMEM];
  const int t = threadIdx.x;
  const int mol = blockIdx.x & 31, sib = blockIdx.x >> 5;   // sib in [0,32)
  const int nbase = mol*128;
  const int abase = nbase + sib*4;                           // own 4 atoms
  unsigned* xhp = (unsigned*)(smem + E_XHP);
  unsigned char* nb8 = (unsigned char*)(smem + E_NB);
  float* prj  = smem + E_PRJ;
  float* pw1s = smem + E_PW1;
  unsigned* er = (unsigned*)(smem + E_ER);

  for(int i=t;i<1280;i+=512){
    int r=i/10, p=i%10;
    xhp[r*21+p]    = xt_p[(nbase+r)*10+p];
    xhp[r*21+10+p] = h_p[rpar*NA*10 + (nbase+r)*10+p];
  }
  if (t < 128) nb8[t] = (unsigned char)(ps[abase*DEG + t] - nbase);
  if (t < 4)  prj[t] = proj0[abase+t];
  if (t < 20) pw1s[t] = pw1[t];
  __syncthreads();

  // env via MFMA (verified fragments); waves 0-3 x 1 atom
  {
    const int wv = t>>6, l = t&63, lg = (t>>4)&3, lr = t&15;
    if (wv < 4){
      f32x4 z4 = {0.f,0.f,0.f,0.f};
      int a = wv;
      int atom_g = abase + a;
      const U4* ap = (const U4*)(Amf + (unsigned)atom_g*512u + (unsigned)l*8u);
      U4 A0 = ap[0], A1 = ap[1];
      const unsigned* nbw = (const unsigned*)(nb8 + a*32 + lg*8);
      unsigned nw0=nbw[0], nw1=nbw[1];
      int nl[8];
      #pragma unroll
      for(int j2=0;j2<4;j2++){ nl[j2]=(nw0>>(8*j2))&255; nl[4+j2]=(nw1>>(8*j2))&255; }
      f32x4 d00,d01,d02,d10,d11,d12;
      {
        UU B; int f=lr; unsigned sh=(f&1)<<4;
        #pragma unroll
        for(int q=0;q<4;q++){
          unsigned wlo = xhp[nl[2*q]*21 + (f>>1)];
          unsigned whi = xhp[nl[2*q+1]*21 + (f>>1)];
          B.u[q] = ((wlo>>sh)&0xffffu) | (((whi>>sh)&0xffffu)<<16);
        }
        d00=__builtin_amdgcn_mfma_f32_16x16x32_bf16(A0.v,B.v,z4,0,0,0);
        d10=__builtin_amdgcn_mfma_f32_16x16x32_bf16(A1.v,B.v,z4,0,0,0);
      }
      {
        UU B; int f=16+lr; unsigned sh=(f&1)<<4;
        #pragma unroll
        for(int q=0;q<4;q++){
          unsigned wlo = xhp[nl[2*q]*21 + (f>>1)];
          unsigned whi = xhp[nl[2*q+1]*21 + (f>>1)];
          B.u[q] = ((wlo>>sh)&0xffffu) | (((whi>>sh)&0xffffu)<<16);
        }
        d01=__builtin_amdgcn_mfma_f32_16x16x32_bf16(A0.v,B.v,z4,0,0,0);
        d11=__builtin_amdgcn_mfma_f32_16x16x32_bf16(A1.v,B.v,z4,0,0,0);
      }
      {
        UU B; int f=32+lr; unsigned sh=(f&1)<<4; int val=(f<40);
        #pragma unroll
        for(int q=0;q<4;q++){
          if (val){
            unsigned wlo = xhp[nl[2*q]*21 + (f>>1)];
            unsigned whi = xhp[nl[2*q+1]*21 + (f>>1)];
            B.u[q] = ((wlo>>sh)&0xffffu) | (((whi>>sh)&0xffffu)<<16);
          } else B.u[q] = 0u;
        }
        d02=__builtin_amdgcn_mfma_f32_16x16x32_bf16(A0.v,B.v,z4,0,0,0);
        d12=__builtin_amdgcn_mfma_f32_16x16x32_bf16(A1.v,B.v,z4,0,0,0);
      }
      unsigned* era = er + a*436;
      wr_tile(era,d00,0,0,lg,lr,l); wr_tile(era,d01,0,1,lg,lr,l);
      wr_tile(era,d02,0,2,lg,lr,l); wr_tile(era,d10,1,0,lg,lr,l);
      wr_tile(era,d11,1,1,lg,lr,l); wr_tile(era,d12,1,2,lg,lr,l);
    }
  }
  if (t < 80){ int a=t/20, f2=t%20; er[a*436+400+f2] = xhp[(sib*4+a)*21+f2]; }
  if (t < 64) er[(t>>4)*436 + 420 + (t&15)] = 0u;
  __syncthreads();

  // MFMA GEMM K=864 (verified); A rows map (l&15)&3; D rows 4-15 discarded
  float* tmp_s = smem + E_TMP;
  if (t < 320){
    int wv = t >> 6, l = t & 63;
    f32x4 cacc = {0.f,0.f,0.f,0.f};
    const unsigned* abase_p = er + ((l & 15)&3)*436 + ((l>>4)<<2);
    const short8v* bptr = (const short8v*)Wmf + (wv*64 + l);
    #pragma unroll 3
    for(int slab=0; slab<27; ++slab){
      short8v av = *(const short8v*)(abase_p + slab*16);
      short8v bv = bptr[slab*320];
      cacc = __builtin_amdgcn_mfma_f32_16x16x32_bf16(av, bv, cacc, 0,0,0);
    }
    int g = wv*16 + (l & 15);
    float wb = Wb[g];
    int r0 = (l>>4)*4;
    #pragma unroll
    for(int r=0;r<4;r++) tmp_s[(r0+r)*80 + g] = cacc[r] + wb;
  }
  __syncthreads();

  // LSTM + h/x0 writes (own 4 atoms)
  float* red = smem + E_RED;
  float* ht  = smem + E_HT;
  if (t < 80){
    int a=t/20, u=t%20;
    float4 tv = *(const float4*)(tmp_s + a*80 + u*4);
    float cold = c_g[(abase+a)*20+u];
    float cnew = sigmoid_f(tv.y)*cold + sigmoid_f(tv.x)*tanh_f(tv.z);
    float og   = sigmoid_f(tv.w);
    c_g[(abase+a)*20+u] = cnew;
    ht[a*20+u]  = og*tanh_f(cnew);
    red[a*20+u] = og*pw1s[u];
  }
  __syncthreads();
  if (t < 40){
    int a=t/10, p=t%10;
    h_po[wpar*NA*10 + (abase+a)*10+p] = bf16pack(ht[a*20+2*p], ht[a*20+2*p+1]);
  }
  if (t < 4){
    float accx = prj[t];
    #pragma unroll
    for(int u=0;u<20;u++) accx += red[t*20+u];
    x0g[abase+t] = accx;
    if (out_col >= 0) outp[(abase+t)*3+out_col] = accx;
  }
}

extern "C" void kernel_launch(void* const* d_in, const int* in_sizes, int n_in,
                              void* d_out, int out_size, void* d_ws, size_t ws_size,
                              hipStream_t stream)
{
  const int*   species = (const int*)  d_in[0];
  const float* coord   = (const float*)d_in[1];
  const float* xh      = (const float*)d_in[2];
  const float* xraw    = (const float*)d_in[3];
  const int*   pf      = (const int*)  d_in[4];
  const int*   ps      = (const int*)  d_in[5];
  const float* h0_intw = (const float*)d_in[6];
  const float* h0_sw   = (const float*)d_in[7];
  const float* h0_sb   = (const float*)d_in[8];
  const float* h0_aw   = (const float*)d_in[9];
  const float* h0_ab   = (const float*)d_in[10];
  const float* h1_intw = (const float*)d_in[11];
  const float* h1_sw   = (const float*)d_in[12];
  const float* h1_sb   = (const float*)d_in[13];
  const float* h1_aw   = (const float*)d_in[14];
  const float* h1_ab   = (const float*)d_in[15];
  const float* W_intw  = (const float*)d_in[16];
  const float* W_sw    = (const float*)d_in[17];
  const float* W_sb    = (const float*)d_in[18];
  const float* pw0     = (const float*)d_in[19];
  const float* pw1     = (const float*)d_in[20];
  const float* pb1     = (const float*)d_in[21];
  float* outp = (float*)d_out;
  (void)pf;

  float* w = (float*)d_ws;
  unsigned short* svA = (unsigned short*)w;  w += NA*320;
  unsigned* Amf = (unsigned*)w;              w += NA*512;
  bf16* Wmf = (bf16*)w;                      w += 34560;
  float* proj0 = w;                          w += NA;
  unsigned* xt_pA = (unsigned*)w;            w += NA*10;
  unsigned* xt_pB = (unsigned*)w;            w += NA*10;
  unsigned* h_p = (unsigned*)w;              w += 2*NA*10;
  float* x0g = w;                            w += NA;
  float* c_g = w;                            w += NA*20;

  k_init<<<1167,512,0,stream>>>(ps,species,coord,xh,xraw,pw0,pb1,W_intw,W_sw,
                                h0_intw,h0_sw,h0_sb,h0_aw,h0_ab,
                                h1_intw,h1_sw,h1_sb,h1_aw,h1_ab,
                                svA,Amf,Wmf,proj0,c_g,h_p,xt_pA,xt_pB);
  for(int step=0; step<5; ++step){
    int rpar = (step+1)&1, wpar = step&1;
    int out_col = (step>=2)? (step-2) : -1;
    unsigned* xtp = (step&1)? xt_pB : xt_pA;
    if (step >= 2)
      k_xt<<<512,256,0,stream>>>(ps,svA,x0g,
                                 h1_intw,h1_sw,h1_sb,h1_aw,h1_ab, xtp);
    k_env<<<1024,512,0,stream>>>(ps,Amf,xtp,h_p,rpar,wpar,
                                 Wmf,W_sb,pw1,proj0,
                                 c_g,h_p,x0g,outp,out_col);
  }
}

// Round 20
// 89.825 us; speedup vs baseline: 1.0878x; 1.0878x over previous
//
#include <hip/hip_runtime.h>
#include <hip/hip_bf16.h>

// Round 20: REVERT to round-18 champion (90.1us). r19's 4-atom k_env split
// doubled total GEMM work (block-GEMM cost is atom-count-independent: 5
// waves x 27 MFMA per block) and doubled staging traffic -> regression.
// 8 atoms/block (16-row A-tile, 2x redundancy) is the profitable floor.
// Chain: k_init (prep|f0|xt0|xt1 overlapped) -> 5 x k_env (+3 k_xt).

#define DEG 32
#define NA 4096
#define NP 131072

typedef __hip_bfloat16 bf16;
typedef __attribute__((ext_vector_type(8))) short short8v;
typedef __attribute__((ext_vector_type(4))) float f32x4;

#define Z0F 16.27906976744186f
#define DZ  1.0526315789473684f

__device__ __forceinline__ float frcp(float x){ return __builtin_amdgcn_rcpf(x); }
__device__ __forceinline__ float sigmoid_f(float x){ return frcp(1.f + __expf(-x)); }
__device__ __forceinline__ float tanh_f(float x){ return 1.f - 2.f*frcp(__expf(2.f*x)+1.f); }
__device__ __forceinline__ float softplus_f(float x){ return fmaxf(x,0.f) + __logf(1.f + __expf(-fabsf(x))); }
__device__ __forceinline__ unsigned bf16pack(float lo, float hi){
  unsigned ul = __float_as_uint(lo), uh = __float_as_uint(hi);
  unsigned rl = (ul + 0x7fffu + ((ul>>16)&1u)) >> 16;
  unsigned rh = (uh + 0x7fffu + ((uh>>16)&1u)) & 0xffff0000u;
  return rl | rh;
}
__device__ __forceinline__ unsigned short b16u(float v){
  unsigned u = __float_as_uint(v);
  return (unsigned short)((u + 0x7fffu + ((u>>16)&1u)) >> 16);
}
union UU { unsigned u[4]; short8v v; };
union U4 { uint4 q; short8v v; unsigned u[4]; };

// write one 16x16 D-tile (rows s<20, cols f<40) into er bf16-pair buffer (r6)
__device__ __forceinline__ void wr_tile(unsigned* er, f32x4 D, int M, int N,
                                        int lg, int lr, int l){
  #pragma unroll
  for(int r=0;r<4;r++){
    float vd = D[r];
    float pr = __shfl_xor(vd, 1);
    int s = M*16 + lg*4 + r, f = N*16 + lr;
    if(!(l&1) && s<20 && f<40) er[s*20 + (f>>1)] = bf16pack(vd, pr);
  }
}

// ---- ivcu staging helper: own 16 atoms' 512 pairs from coords ----------------
__device__ __forceinline__ void stage_ivcu(float2* ivcu, unsigned char* nb8,
    int t, int abase, int nbase,
    const int* __restrict__ ps, const float* __restrict__ coord){
  int pg = abase*DEG + t;
  int i = abase + (t>>5);
  int j = ps[pg];
  float dx = coord[i*3+0]-coord[j*3+0];
  float dy = coord[i*3+1]-coord[j*3+1];
  float dz = coord[i*3+2]-coord[j*3+2];
  float d = sqrtf(dx*dx+dy*dy+dz*dz + 1e-12f);
  float cu = 0.f;
  if (d < 7.5f){ float c = __cosf(d * 0.20943951023931953f); cu = c*c; } // pi/15
  ivcu[t] = make_float2(1.f/d, cu);
  nb8[t] = (unsigned char)(j - nbase);
}

// ---- merged init kernel LDS (4672 words = 18.7 KB) ---------------------------
#define I_IVCU 0      // float2[512] = 1024 w
#define I_NB   1024   // u8[512] = 128 w
#define I_INDF 1152   // f0: [128*5] = 640
#define I_ENV0 1792   // f0: 1600
#define I_Y0A  3392   // f0: 640
#define I_Y0B  4032   // f0: 640  (ends 4672)
#define I_XIN  1152   // xt: [128]
#define I_WTS  1280   // xt: 1700
#define I_EV1  2980   // xt: 320
#define I_YA   3300   // xt: 320
#define I_YB   3620   // xt: 320 (ends 3940)
#define I_SMEM 4672

// ---------------- k_init: prep (b<399) | f0 | xt0 | xt1 ----------------------
__global__ __launch_bounds__(512) void k_init(
    const int* __restrict__ ps, const int* __restrict__ species,
    const float* __restrict__ coord, const float* __restrict__ xh,
    const float* __restrict__ xraw,
    const float* __restrict__ pw0, const float* __restrict__ pb1,
    const float* __restrict__ Wint, const float* __restrict__ Wself,
    const float* __restrict__ h0_iw, const float* __restrict__ h0_sw,
    const float* __restrict__ h0_sb, const float* __restrict__ h0_aw,
    const float* __restrict__ h0_ab,
    const float* __restrict__ h1_iw, const float* __restrict__ h1_sw,
    const float* __restrict__ h1_sb, const float* __restrict__ h1_aw,
    const float* __restrict__ h1_ab,
    unsigned short* __restrict__ svA, unsigned* __restrict__ Amf,
    bf16* __restrict__ Wmf, float* __restrict__ proj0,
    float* __restrict__ c_g, unsigned* __restrict__ h_p,
    unsigned* __restrict__ xt_p0, unsigned* __restrict__ xt_p1)
{
  __shared__ float smem[I_SMEM];
  const int b = blockIdx.x, t = threadIdx.x;

  if (b < 256){
    // ---- prep: svA + Amf per pair (512 pairs/block)
    int p = b*512 + t;
    int i = p>>5, j = ps[p];
    float dx = coord[i*3+0]-coord[j*3+0];
    float dy = coord[i*3+1]-coord[j*3+1];
    float dz = coord[i*3+2]-coord[j*3+2];
    float d = sqrtf(dx*dx+dy*dy+dz*dz + 1e-12f);
    float cu = 0.f;
    if (d < 7.5f){ float c = __cosf(d * 0.20943951023931953f); cu = c*c; }
    float z0 = (1.f/d - 0.2f)*Z0F;
    int atom = p>>5, k = p&31;
    float sv[20], svn[20];
    #pragma unroll
    for(int s=0;s<20;s++){
      float z = z0 - (float)s*DZ;
      sv[s] = cu*__expf(-0.5f*z*z);
    }
    #pragma unroll
    for(int s=0;s<20;s++) svn[s] = __shfl_down(sv[s], 1);
    #pragma unroll
    for(int s=0;s<20;s++) svA[atom*640 + s*32 + k] = b16u(sv[s]);
    if (!(k&1)){
      int lg = k>>3, q = (k>>1)&3;
      #pragma unroll
      for(int s=0;s<20;s++){
        int lr = s&15, fr = s>>4;
        Amf[atom*512 + (lg*16+lr)*8 + fr*4 + q] = bf16pack(sv[s], svn[s]);
      }
    } else {
      int idx = k>>1;
      int lg2 = idx>>2, q2 = idx&3;
      #pragma unroll
      for(int j2=0;j2<12;j2++){
        int lr = 4+j2;
        Amf[atom*512 + (lg2*16+lr)*8 + 4 + q2] = 0u;
      }
    }
    return;
  }
  if (b < 391){
    // ---- prep: Wmf B-fragment transform
    int tid = (b-256)*512 + t;    // < 69120 exactly
    int j = tid & 7, l = (tid>>3) & 63, gt = (tid>>9)%5, slab = tid/2560;
    int k = slab*32 + ((l>>4)<<3) + j;
    int g = gt*16 + (l&15);
    float v = 0.f;
    if (k < 800)      v = Wint[k*80+g];
    else if (k < 840) v = Wself[(k-800)*80+g];
    Wmf[tid] = __float2bfloat16(v);
    return;
  }
  if (b < 399){
    // ---- prep: proj0
    int tid = (b-391)*512 + t;
    if (tid < NA){
      int sp = species[tid];
      float f0 = (sp==1)?1.f:0.f, f1 = (sp==8)?1.f:0.f;
      proj0[tid] = pb1[0] + f0*pw0[0] + f1*pw0[1] + xh[tid*3+0]*pw0[2]
                 + xh[tid*3+1]*pw0[3] + xh[tid*3+2]*pw0[4];
    }
    return;
  }

  float2* ivcu = (float2*)(smem + I_IVCU);
  unsigned char* nb8 = (unsigned char*)(smem + I_NB);

  if (b < 655){
    // ---- f0 (inline sense; r11-verified loop), own 16 atoms
    int blk = b - 399;
    int mol = blk & 31, sib = blk >> 5;
    int nbase = mol*128, abase = nbase + sib*16;
    float* indf = smem + I_INDF;
    float* env0 = smem + I_ENV0;
    float* y0a  = smem + I_Y0A;
    float* y0b  = smem + I_Y0B;
    stage_ivcu(ivcu, nb8, t, abase, nbase, ps, coord);
    if (t < 128){
      int sp = species[nbase+t];
      indf[t*5+0] = (sp==1)?1.f:0.f;
      indf[t*5+1] = (sp==8)?1.f:0.f;
      indf[t*5+2] = xh[(nbase+t)*3+0];
      indf[t*5+3] = xh[(nbase+t)*3+1];
      indf[t*5+4] = xh[(nbase+t)*3+2];
    }
    __syncthreads();
    for(int task=t; task<1600; task+=512){
      int a = task/100, e = task%100, s = e/5, f = e%5;
      const float2* ivr = ivcu + a*32;
      const unsigned char* nbr = nb8 + a*32;
      float sz = (float)s*DZ, acc = 0.f;
      for(int k=0;k<32;k++){
        float2 vc = ivr[k];
        float z = (vc.x-0.2f)*Z0F - sz;
        acc += vc.y*__expf(-0.5f*z*z)*indf[nbr[k]*5+f];
      }
      env0[a*100+e] = acc;
    }
    __syncthreads();
    for(int task=t; task<640; task+=512){
      int a=task/40, o=task%40, row=(sib*16)+a;
      float acc = h0_sb[o];
      #pragma unroll
      for(int f=0;f<5;f++) acc += indf[row*5+f]*h0_sw[f*40+o];
      for(int e=0;e<100;e++) acc += env0[a*100+e]*h0_iw[e*40+o];
      y0a[a*40+o] = softplus_f(acc);
    }
    __syncthreads();
    float* cur = y0a; float* nxt = y0b;
    for(int l=0;l<3;l++){
      for(int task=t; task<640; task+=512){
        int a=task/40, o=task%40;
        float acc = h0_ab[l*40+o];
        for(int f=0;f<40;f++) acc += cur[a*40+f]*h0_aw[l*1600+f*40+o];
        nxt[a*40+o] = softplus_f(acc);
      }
      __syncthreads();
      float* tswap=cur; cur=nxt; nxt=tswap;
    }
    if (t < 320){ int a=t/20,u=t%20; c_g[(abase+a)*20+u] = cur[a*40+u]; }
    if (t < 160){ int a=t/10,p=t%10;
      h_p[NA*10 + (abase+a)*10+p] = bf16pack(cur[a*40+20+2*p], cur[a*40+21+2*p]); }
    return;
  }

  // ---- xt0 / xt1 (inline sense; r12-verified loop), own 16 atoms
  {
    int sel = (b < 911) ? 0 : 1;
    int blk = b - (sel ? 911 : 655);
    int mol = blk & 31, sib = blk >> 5;
    int nbase = mol*128, abase = nbase + sib*16;
    float* xin = smem + I_XIN;
    float* wts = smem + I_WTS;
    float* ev1 = smem + I_EV1;
    float* yA  = smem + I_YA;
    float* yB  = smem + I_YB;
    unsigned* xt_p = sel ? xt_p1 : xt_p0;

    stage_ivcu(ivcu, nb8, t, abase, nbase, ps, coord);
    if (t < 128) xin[t] = xraw[(nbase+t)*2+sel];
    for(int i=t;i<1700;i+=512){
      float v;
      if(i<400){ int o=i/20,s=i%20; v=h1_iw[s*20+o]; }
      else if(i<420) v=h1_sw[i-400];
      else if(i<440) v=h1_sb[i-420];
      else if(i<1640){ int q=i-440,L=q/400,rem=q%400,o=rem/20,f=rem%20; v=h1_aw[L*400+f*20+o]; }
      else v=h1_ab[i-1640];
      wts[i]=v;
    }
    __syncthreads();
    if (t < 320){
      int a=t/20, s=t%20;
      const float2* ivr = ivcu + a*32;
      const unsigned char* nbr = nb8 + a*32;
      float sz=(float)s*DZ, acc=0.f;
      for(int k=0;k<32;k++){
        float2 vc = ivr[k];
        float z = (vc.x-0.2f)*Z0F - sz;
        acc += vc.y*__expf(-0.5f*z*z)*xin[nbr[k]];
      }
      ev1[t] = acc;
    }
    __syncthreads();
    if (t < 320){
      int a=t/20, o=t%20;
      float acc = wts[420+o] + xin[sib*16+a]*wts[400+o];
      const float* e = ev1 + a*20; const float* w = wts + o*20;
      #pragma unroll
      for(int s=0;s<20;s++) acc += e[s]*w[s];
      yA[t] = softplus_f(acc);
    }
    __syncthreads();
    #pragma unroll
    for(int L=0;L<2;L++){
      const float* src = (L==0)? yA : yB;
      float* dst       = (L==0)? yB : yA;
      if (t < 320){
        int a=t/20, o=t%20;
        float acc = wts[1640+L*20+o];
        const float* sr = src + a*20; const float* w = wts + 440 + L*400 + o*20;
        #pragma unroll
        for(int f=0;f<20;f++) acc += sr[f]*w[f];
        dst[t] = softplus_f(acc);
      }
      __syncthreads();
    }
    if (t < 160){
      int a=t/10, p=t%10, o0=2*p, o1=o0+1;
      const float* e = yA + a*20;
      float a0 = wts[1680+o0], a1 = wts[1680+o1];
      const float* wA = wts + 1240 + o0*20;
      const float* wB = wA + 20;
      #pragma unroll
      for(int f=0;f<20;f++){ a0 += e[f]*wA[f]; a1 += e[f]*wB[f]; }
      xt_p[(abase+a)*10+p] = bf16pack(softplus_f(a0), softplus_f(a1));
    }
  }
}

// ---------------- standalone xt (steps 2-4; r17 svA version) -----------------
#define X_XIN 0
#define X_NB  128
#define X_WTS 256
#define X_EV1 1956
#define X_YA  2276
#define X_YB  2596
__global__ __launch_bounds__(512) void k_xt(
    const int* __restrict__ ps, const unsigned short* __restrict__ svA,
    const float* __restrict__ x0g,
    const float* __restrict__ h1_iw, const float* __restrict__ h1_sw,
    const float* __restrict__ h1_sb, const float* __restrict__ h1_aw,
    const float* __restrict__ h1_ab,
    unsigned* __restrict__ xt_p)
{
  __shared__ float smem[2916];
  const int t = threadIdx.x;
  const int mol = blockIdx.x & 31, sib = blockIdx.x >> 5;
  const int nbase = mol*128;
  const int abase = nbase + sib*16;
  float* xin = smem + X_XIN;
  unsigned char* nb8 = (unsigned char*)(smem + X_NB);
  float* wts = smem + X_WTS;
  float* ev1 = smem + X_EV1;
  float* yA  = smem + X_YA;
  float* yB  = smem + X_YB;

  if (t < 128) xin[t] = x0g[nbase+t];
  nb8[t] = (unsigned char)(ps[abase*DEG+t] - nbase);
  for(int i=t;i<1700;i+=512){
    float v;
    if(i<400){ int o=i/20,s=i%20; v=h1_iw[s*20+o]; }
    else if(i<420) v=h1_sw[i-400];
    else if(i<440) v=h1_sb[i-420];
    else if(i<1640){ int q=i-440,L=q/400,rem=q%400,o=rem/20,f=rem%20; v=h1_aw[L*400+f*20+o]; }
    else v=h1_ab[i-1640];
    wts[i]=v;
  }
  __syncthreads();

  if (t < 320){
    int a=t/20, s=t%20;
    const uint4* sp4 = (const uint4*)(svA + (abase+a)*640 + s*32);
    const unsigned char* nbr = nb8 + a*32;
    float acc = 0.f;
    #pragma unroll
    for(int c4=0;c4<4;c4++){
      uint4 w = sp4[c4];
      unsigned wu[4] = {w.x,w.y,w.z,w.w};
      #pragma unroll
      for(int j=0;j<4;j++){
        float flo = __uint_as_float(wu[j]<<16);
        float fhi = __uint_as_float(wu[j] & 0xffff0000u);
        int k = c4*8 + 2*j;
        acc += flo*xin[nbr[k]] + fhi*xin[nbr[k+1]];
      }
    }
    ev1[t] = acc;
  }
  __syncthreads();
  if (t < 320){
    int a=t/20, o=t%20;
    float acc = wts[420+o] + xin[sib*16+a]*wts[400+o];
    const float* e = ev1 + a*20; const float* w = wts + o*20;
    #pragma unroll
    for(int s=0;s<20;s++) acc += e[s]*w[s];
    yA[t] = softplus_f(acc);
  }
  __syncthreads();
  #pragma unroll
  for(int L=0;L<2;L++){
    const float* src = (L==0)? yA : yB;
    float* dst       = (L==0)? yB : yA;
    if (t < 320){
      int a=t/20, o=t%20;
      float acc = wts[1640+L*20+o];
      const float* sr = src + a*20; const float* w = wts + 440 + L*400 + o*20;
      #pragma unroll
      for(int f=0;f<20;f++) acc += sr[f]*w[f];
      dst[t] = softplus_f(acc);
    }
    __syncthreads();
  }
  if (t < 160){
    int a=t/10, p=t%10, o0=2*p, o1=o0+1;
    const float* e = yA + a*20;
    float a0 = wts[1680+o0], a1 = wts[1680+o1];
    const float* wA = wts + 1240 + o0*20;
    const float* wB = wA + 20;
    #pragma unroll
    for(int f=0;f<20;f++){ a0 += e[f]*wA[f]; a1 += e[f]*wB[f]; }
    xt_p[(abase+a)*10+p] = bf16pack(softplus_f(a0), softplus_f(a1));
  }
}

// ---------------- k_env: 512 blocks x 8 atoms (r17/r18-verified) -------------
#define E_XHP 0
#define E_NB  2688
#define E_PRJ 2752
#define E_PW1 2768
#define E_ER  2792
#define E_TMP (E_ER+6976)
#define E_RED (E_TMP+1280)
#define E_HT  (E_RED+160)
#define E_SMEM (E_HT+160)
__global__ __launch_bounds__(512) void k_env(
    const int* __restrict__ ps, const unsigned* __restrict__ Amf,
    const unsigned* __restrict__ xt_p, const unsigned* __restrict__ h_p,
    int rpar, int wpar,
    const bf16* __restrict__ Wmf, const float* __restrict__ Wb,
    const float* __restrict__ pw1, const float* __restrict__ proj0,
    float* __restrict__ c_g, unsigned* __restrict__ h_po,
    float* __restrict__ x0g, float* __restrict__ outp, int out_col)
{
  __shared__ float smem[E_SMEM];
  const int t = threadIdx.x;
  const int mol = blockIdx.x & 31, sib = blockIdx.x >> 5;   // sib in [0,16)
  const int nbase = mol*128;
  const int abase = nbase + sib*8;                           // own 8 atoms
  unsigned* xhp = (unsigned*)(smem + E_XHP);
  unsigned char* nb8 = (unsigned char*)(smem + E_NB);
  float* prj  = smem + E_PRJ;
  float* pw1s = smem + E_PW1;
  unsigned* er = (unsigned*)(smem + E_ER);

  for(int i=t;i<1280;i+=512){
    int r=i/10, p=i%10;
    xhp[r*21+p]    = xt_p[(nbase+r)*10+p];
    xhp[r*21+10+p] = h_p[rpar*NA*10 + (nbase+r)*10+p];
  }
  if (t < 256) nb8[t] = (unsigned char)(ps[abase*DEG + t] - nbase);
  if (t < 8)  prj[t] = proj0[abase+t];
  if (t < 20) pw1s[t] = pw1[t];
  __syncthreads();

  // env via MFMA (r6/r12/r14-verified fragments); 8 waves x 1 atom
  {
    const int wv = t>>6, l = t&63, lg = (t>>4)&3, lr = t&15;
    f32x4 z4 = {0.f,0.f,0.f,0.f};
    int a = wv;
    int atom_g = abase + a;
    const U4* ap = (const U4*)(Amf + (unsigned)atom_g*512u + (unsigned)l*8u);
    U4 A0 = ap[0], A1 = ap[1];
    const unsigned* nbw = (const unsigned*)(nb8 + a*32 + lg*8);
    unsigned nw0=nbw[0], nw1=nbw[1];
    int nl[8];
    #pragma unroll
    for(int j2=0;j2<4;j2++){ nl[j2]=(nw0>>(8*j2))&255; nl[4+j2]=(nw1>>(8*j2))&255; }
    f32x4 d00,d01,d02,d10,d11,d12;
    {
      UU B; int f=lr; unsigned sh=(f&1)<<4;
      #pragma unroll
      for(int q=0;q<4;q++){
        unsigned wlo = xhp[nl[2*q]*21 + (f>>1)];
        unsigned whi = xhp[nl[2*q+1]*21 + (f>>1)];
        B.u[q] = ((wlo>>sh)&0xffffu) | (((whi>>sh)&0xffffu)<<16);
      }
      d00=__builtin_amdgcn_mfma_f32_16x16x32_bf16(A0.v,B.v,z4,0,0,0);
      d10=__builtin_amdgcn_mfma_f32_16x16x32_bf16(A1.v,B.v,z4,0,0,0);
    }
    {
      UU B; int f=16+lr; unsigned sh=(f&1)<<4;
      #pragma unroll
      for(int q=0;q<4;q++){
        unsigned wlo = xhp[nl[2*q]*21 + (f>>1)];
        unsigned whi = xhp[nl[2*q+1]*21 + (f>>1)];
        B.u[q] = ((wlo>>sh)&0xffffu) | (((whi>>sh)&0xffffu)<<16);
      }
      d01=__builtin_amdgcn_mfma_f32_16x16x32_bf16(A0.v,B.v,z4,0,0,0);
      d11=__builtin_amdgcn_mfma_f32_16x16x32_bf16(A1.v,B.v,z4,0,0,0);
    }
    {
      UU B; int f=32+lr; unsigned sh=(f&1)<<4; int val=(f<40);
      #pragma unroll
      for(int q=0;q<4;q++){
        if (val){
          unsigned wlo = xhp[nl[2*q]*21 + (f>>1)];
          unsigned whi = xhp[nl[2*q+1]*21 + (f>>1)];
          B.u[q] = ((wlo>>sh)&0xffffu) | (((whi>>sh)&0xffffu)<<16);
        } else B.u[q] = 0u;
      }
      d02=__builtin_amdgcn_mfma_f32_16x16x32_bf16(A0.v,B.v,z4,0,0,0);
      d12=__builtin_amdgcn_mfma_f32_16x16x32_bf16(A1.v,B.v,z4,0,0,0);
    }
    unsigned* era = er + a*436;
    wr_tile(era,d00,0,0,lg,lr,l); wr_tile(era,d01,0,1,lg,lr,l);
    wr_tile(era,d02,0,2,lg,lr,l); wr_tile(era,d10,1,0,lg,lr,l);
    wr_tile(era,d11,1,1,lg,lr,l); wr_tile(era,d12,1,2,lg,lr,l);
  }
  if (t < 160){ int a=t/20, f2=t%20; er[a*436+400+f2] = xhp[(sib*8+a)*21+f2]; }
  if (t < 256) er[(t>>4)*436 + 420 + (t&15)] = 0u;
  __syncthreads();

  // MFMA GEMM K=864; A rows 8-15 computed-and-discarded (LSTM reads a<8)
  float* tmp_s = smem + E_TMP;
  if (t < 320){
    int wv = t >> 6, l = t & 63;
    f32x4 cacc = {0.f,0.f,0.f,0.f};
    const unsigned* abase_p = er + (l & 15)*436 + ((l>>4)<<2);
    const short8v* bptr = (const short8v*)Wmf + (wv*64 + l);
    #pragma unroll 3
    for(int slab=0; slab<27; ++slab){
      short8v av = *(const short8v*)(abase_p + slab*16);
      short8v bv = bptr[slab*320];
      cacc = __builtin_amdgcn_mfma_f32_16x16x32_bf16(av, bv, cacc, 0,0,0);
    }
    int g = wv*16 + (l & 15);
    float wb = Wb[g];
    int r0 = (l>>4)*4;
    #pragma unroll
    for(int r=0;r<4;r++) tmp_s[(r0+r)*80 + g] = cacc[r] + wb;
  }
  __syncthreads();

  // LSTM + h/x0 writes (own 8 atoms)
  float* red = smem + E_RED;
  float* ht  = smem + E_HT;
  if (t < 160){
    int a=t/20, u=t%20;
    float4 tv = *(const float4*)(tmp_s + a*80 + u*4);
    float cold = c_g[(abase+a)*20+u];
    float cnew = sigmoid_f(tv.y)*cold + sigmoid_f(tv.x)*tanh_f(tv.z);
    float og   = sigmoid_f(tv.w);
    c_g[(abase+a)*20+u] = cnew;
    ht[a*20+u]  = og*tanh_f(cnew);
    red[a*20+u] = og*pw1s[u];
  }
  __syncthreads();
  if (t < 80){
    int a=t/10, p=t%10;
    h_po[wpar*NA*10 + (abase+a)*10+p] = bf16pack(ht[a*20+2*p], ht[a*20+2*p+1]);
  }
  if (t < 8){
    float accx = prj[t];
    #pragma unroll
    for(int u=0;u<20;u++) accx += red[t*20+u];
    x0g[abase+t] = accx;
    if (out_col >= 0) outp[(abase+t)*3+out_col] = accx;
  }
}

extern "C" void kernel_launch(void* const* d_in, const int* in_sizes, int n_in,
                              void* d_out, int out_size, void* d_ws, size_t ws_size,
                              hipStream_t stream)
{
  const int*   species = (const int*)  d_in[0];
  const float* coord   = (const float*)d_in[1];
  const float* xh      = (const float*)d_in[2];
  const float* xraw    = (const float*)d_in[3];
  const int*   pf      = (const int*)  d_in[4];
  const int*   ps      = (const int*)  d_in[5];
  const float* h0_intw = (const float*)d_in[6];
  const float* h0_sw   = (const float*)d_in[7];
  const float* h0_sb   = (const float*)d_in[8];
  const float* h0_aw   = (const float*)d_in[9];
  const float* h0_ab   = (const float*)d_in[10];
  const float* h1_intw = (const float*)d_in[11];
  const float* h1_sw   = (const float*)d_in[12];
  const float* h1_sb   = (const float*)d_in[13];
  const float* h1_aw   = (const float*)d_in[14];
  const float* h1_ab   = (const float*)d_in[15];
  const float* W_intw  = (const float*)d_in[16];
  const float* W_sw    = (const float*)d_in[17];
  const float* W_sb    = (const float*)d_in[18];
  const float* pw0     = (const float*)d_in[19];
  const float* pw1     = (const float*)d_in[20];
  const float* pb1     = (const float*)d_in[21];
  float* outp = (float*)d_out;
  (void)pf;

  float* w = (float*)d_ws;
  unsigned short* svA = (unsigned short*)w;  w += NA*320;   // 640 u16/atom
  unsigned* Amf = (unsigned*)w;              w += NA*512;   // A-frags, 8MB
  bf16* Wmf = (bf16*)w;                      w += 34560;    // 69120 bf16
  float* proj0 = w;                          w += NA;
  unsigned* xt_pA = (unsigned*)w;            w += NA*10;
  unsigned* xt_pB = (unsigned*)w;            w += NA*10;
  unsigned* h_p = (unsigned*)w;              w += 2*NA*10;
  float* x0g = w;                            w += NA;
  float* c_g = w;                            w += NA*20;

  k_init<<<1167,512,0,stream>>>(ps,species,coord,xh,xraw,pw0,pb1,W_intw,W_sw,
                                h0_intw,h0_sw,h0_sb,h0_aw,h0_ab,
                                h1_intw,h1_sw,h1_sb,h1_aw,h1_ab,
                                svA,Amf,Wmf,proj0,c_g,h_p,xt_pA,xt_pB);
  for(int step=0; step<5; ++step){
    int rpar = (step+1)&1, wpar = step&1;
    int out_col = (step>=2)? (step-2) : -1;
    unsigned* xtp = (step&1)? xt_pB : xt_pA;
    if (step >= 2)
      k_xt<<<256,512,0,stream>>>(ps,svA,x0g,
                                 h1_intw,h1_sw,h1_sb,h1_aw,h1_ab, xtp);
    k_env<<<512,512,0,stream>>>(ps,Amf,xtp,h_p,rpar,wpar,
                                Wmf,W_sb,pw1,proj0,
                                c_g,h_p,x0g,outp,out_col);
  }
}